// Round 15
// baseline (854.091 us; speedup 1.0000x reference)
//
#include <hip/hip_runtime.h>
#include <hip/hip_bf16.h>
#include <stdint.h>

#define SQ 2048
#define DK 64
#define NB 32
#define TQ 16              // q rows per block
#define KH 1024            // k-half per block
#define EW 1032            // bf16 elems per LDS row (1024 + 8 pad)
#define SCL 0.18033688011112042f   // log2(e)/8

typedef __attribute__((ext_vector_type(8))) short short8;
typedef __attribute__((ext_vector_type(4))) float f32x4;
typedef __attribute__((ext_vector_type(4))) unsigned u32x4;
typedef __attribute__((ext_vector_type(2))) unsigned u32x2;

// ---- bf16 helpers ----
__device__ __forceinline__ unsigned f2bf_u(float x) {
    unsigned u = __builtin_bit_cast(unsigned, x);
    u += 0x7fffu + ((u >> 16) & 1u);
    return u >> 16;
}
__device__ __forceinline__ float bf2f(unsigned h) {
    return __builtin_bit_cast(float, h << 16);
}
__device__ __forceinline__ float bf2f_hi(unsigned u) {
    return __builtin_bit_cast(float, u & 0xffff0000u);
}
__device__ __forceinline__ unsigned cvtpk_bf16(float lo, float hi) {
    unsigned r;
    asm("v_cvt_pk_bf16_f32 %0, %1, %2" : "=v"(r) : "v"(lo), "v"(hi));
    return r;
}
__device__ __forceinline__ void split8(const float* p, short8& h, short8& l) {
    f32x4 a = *(const f32x4*)p;
    f32x4 b = *(const f32x4*)(p + 4);
    #pragma unroll
    for (int j = 0; j < 4; ++j) {
        unsigned ua = f2bf_u(a[j]);
        h[j] = (short)ua; l[j] = (short)f2bf_u(a[j] - bf2f(ua));
        unsigned ub = f2bf_u(b[j]);
        h[j + 4] = (short)ub; l[j + 4] = (short)f2bf_u(b[j] - bf2f(ub));
    }
}

// ============ fused prep: K planes + Vt transpose + mask bitpack ============
__global__ __launch_bounds__(256) void prep_kernel(
    const float* __restrict__ K, const float* __restrict__ V,
    const unsigned* __restrict__ Mk,
    unsigned short* __restrict__ Khi, unsigned short* __restrict__ Klo,
    unsigned short* __restrict__ Vt, unsigned* __restrict__ Mkb)
{
    __shared__ float vtile[64][65];
    const int t = threadIdx.x;

    if (blockIdx.x >= NB * 32) {
        const size_t w = (size_t)(blockIdx.x - NB * 32) * 256 + t;
        const unsigned* p = Mk + w * 32;
        unsigned bits = 0;
        #pragma unroll
        for (int j = 0; j < 8; ++j) {
            const u32x4 v = *(const u32x4*)(p + j * 4);
            bits |= (v[0] ? 1u : 0u) << (j * 4 + 0);
            bits |= (v[1] ? 1u : 0u) << (j * 4 + 1);
            bits |= (v[2] ? 1u : 0u) << (j * 4 + 2);
            bits |= (v[3] ? 1u : 0u) << (j * 4 + 3);
        }
        Mkb[w] = bits;
        return;
    }

    const int b  = blockIdx.x >> 5;
    const int s0 = (blockIdx.x & 31) << 6;
    const size_t base = ((size_t)b * SQ + s0) * DK + (size_t)t * 16;

    {
        short8 h0, l0, h1, l1;
        split8(K + base,     h0, l0);
        split8(K + base + 8, h1, l1);
        *(short8*)(Khi + base)     = h0;
        *(short8*)(Khi + base + 8) = h1;
        *(short8*)(Klo + base)     = l0;
        *(short8*)(Klo + base + 8) = l1;
    }
    {
        const int sr = t >> 2, dc = (t & 3) << 4;
        #pragma unroll
        for (int u = 0; u < 16; u += 4) {
            f32x4 v = *(const f32x4*)(V + base + u);
            vtile[sr][dc + u + 0] = v[0];
            vtile[sr][dc + u + 1] = v[1];
            vtile[sr][dc + u + 2] = v[2];
            vtile[sr][dc + u + 3] = v[3];
        }
    }
    __syncthreads();
    #pragma unroll
    for (int rep = 0; rep < 16; ++rep) {
        const int idx = rep * 256 + t;
        const int d = idx >> 6, s = idx & 63;
        Vt[((size_t)b * DK + d) * SQ + s0 + s] = (unsigned short)f2bf_u(vtile[s][d]);
    }
}

// ============ main: k-split blocks, 4 blocks/CU, full occupancy ============
__global__ __launch_bounds__(512, 8) void sdpa_main(
    const float* __restrict__ Q, const unsigned short* __restrict__ Khi,
    const unsigned short* __restrict__ Klo, const unsigned short* __restrict__ Vt,
    const unsigned* __restrict__ Mkb, float* __restrict__ Yp, float* __restrict__ Aout)
{
    __shared__ __align__(16) unsigned short e_half[TQ][EW];  // 33 KB, masked-e bf16
    __shared__ float yp[4][TQ][16];                          // 4 KB
    __shared__ float rsum[8][TQ];                            // 512 B
    __shared__ float i2s[TQ];

    const int tid  = threadIdx.x;
    const int lane = tid & 63;
    const int wv   = tid >> 6;          // 0..7
    const int m16  = lane & 15;
    const int kq   = lane >> 4;
    const int koff = kq * 8;

    // XCD batch-affinity swizzle: XCD x owns batches 4x..4x+3
    const int bx   = blockIdx.x;
    const int xcd  = bx & 7;
    const int j    = bx >> 3;           // 0..1023
    const int b    = xcd * 4 + (j >> 8);
    const int rest = j & 255;
    const int q0   = (rest >> 1) * TQ;
    const int kh   = rest & 1;

    const int wlocal = wv & 3;                 // strip index within own half
    const bool owned = (wv >> 2) == kh;

    // Q fragments (B-operand), split bf16
    short8 qh[2], ql[2];
    {
        const float* qrow = Q + ((size_t)b * SQ + q0 + m16) * DK;
        split8(qrow + koff,      qh[0], ql[0]);
        split8(qrow + 32 + koff, qh[1], ql[1]);
    }

    // ---- Phase A: full-k rowsum; owned waves also mask+pack -> LDS ----
    float rs = 0.f;
    {
        const size_t krow = ((size_t)b * SQ + wv * 256 + m16) * DK;
        const unsigned short* khp = Khi + krow;
        const unsigned short* klp = Klo + krow;
        const int xw = (m16 & 7) << 3;

        if (owned) {
            // bitmask for this wave's 256-k strip (L2-resident)
            const unsigned* mrow = Mkb + ((size_t)b * SQ + q0 + m16) * (SQ / 32) + wv * 8;
            const u32x4 mA = *(const u32x4*)mrow;
            const u32x4 mB = *(const u32x4*)(mrow + 4);
            #pragma unroll
            for (int t = 0; t < 16; ++t) {
                const int off = t * 16 * DK;
                const short8 kh0 = *(const short8*)(khp + off + koff);
                const short8 kh1 = *(const short8*)(khp + off + 32 + koff);
                const short8 kl0 = *(const short8*)(klp + off + koff);
                const short8 kl1 = *(const short8*)(klp + off + 32 + koff);
                f32x4 a0 = {0.f, 0.f, 0.f, 0.f};
                f32x4 a1 = {0.f, 0.f, 0.f, 0.f};
                a0 = __builtin_amdgcn_mfma_f32_16x16x32_bf16(kh0, qh[0], a0, 0, 0, 0);
                a1 = __builtin_amdgcn_mfma_f32_16x16x32_bf16(kh1, qh[1], a1, 0, 0, 0);
                a0 = __builtin_amdgcn_mfma_f32_16x16x32_bf16(kh0, ql[0], a0, 0, 0, 0);
                a1 = __builtin_amdgcn_mfma_f32_16x16x32_bf16(kh1, ql[1], a1, 0, 0, 0);
                a0 = __builtin_amdgcn_mfma_f32_16x16x32_bf16(kl0, qh[0], a0, 0, 0, 0);
                a1 = __builtin_amdgcn_mfma_f32_16x16x32_bf16(kl1, qh[1], a1, 0, 0, 0);
                const float e0 = __builtin_amdgcn_exp2f((a0[0] + a1[0]) * SCL);
                const float e1 = __builtin_amdgcn_exp2f((a0[1] + a1[1]) * SCL);
                const float e2 = __builtin_amdgcn_exp2f((a0[2] + a1[2]) * SCL);
                const float e3 = __builtin_amdgcn_exp2f((a0[3] + a1[3]) * SCL);
                rs += (e0 + e1) + (e2 + e3);
                const unsigned mword = (t < 8) ? mA[t >> 1] : mB[(t >> 1) - 4];
                const unsigned bits = mword >> ((t & 1) * 16 + kq * 4);
                const float p0 = (bits & 1u) ? e0 : 0.f;
                const float p1 = (bits & 2u) ? e1 : 0.f;
                const float p2 = (bits & 4u) ? e2 : 0.f;
                const float p3 = (bits & 8u) ? e3 : 0.f;
                u32x2 pk;
                pk[0] = cvtpk_bf16(p0, p1);
                pk[1] = cvtpk_bf16(p2, p3);
                *(u32x2*)&e_half[m16][(wlocal * 256 + t * 16 + kq * 4) ^ xw] = pk;
            }
        } else {
            #pragma unroll
            for (int t = 0; t < 16; ++t) {
                const int off = t * 16 * DK;
                const short8 kh0 = *(const short8*)(khp + off + koff);
                const short8 kh1 = *(const short8*)(khp + off + 32 + koff);
                const short8 kl0 = *(const short8*)(klp + off + koff);
                const short8 kl1 = *(const short8*)(klp + off + 32 + koff);
                f32x4 a0 = {0.f, 0.f, 0.f, 0.f};
                f32x4 a1 = {0.f, 0.f, 0.f, 0.f};
                a0 = __builtin_amdgcn_mfma_f32_16x16x32_bf16(kh0, qh[0], a0, 0, 0, 0);
                a1 = __builtin_amdgcn_mfma_f32_16x16x32_bf16(kh1, qh[1], a1, 0, 0, 0);
                a0 = __builtin_amdgcn_mfma_f32_16x16x32_bf16(kh0, ql[0], a0, 0, 0, 0);
                a1 = __builtin_amdgcn_mfma_f32_16x16x32_bf16(kh1, ql[1], a1, 0, 0, 0);
                a0 = __builtin_amdgcn_mfma_f32_16x16x32_bf16(kl0, qh[0], a0, 0, 0, 0);
                a1 = __builtin_amdgcn_mfma_f32_16x16x32_bf16(kl1, qh[1], a1, 0, 0, 0);
                rs += (__builtin_amdgcn_exp2f((a0[0] + a1[0]) * SCL)
                     + __builtin_amdgcn_exp2f((a0[1] + a1[1]) * SCL))
                    + (__builtin_amdgcn_exp2f((a0[2] + a1[2]) * SCL)
                     + __builtin_amdgcn_exp2f((a0[3] + a1[3]) * SCL));
            }
        }
    }
    rs += __shfl_xor(rs, 16);
    rs += __shfl_xor(rs, 32);
    if (lane < 16) rsum[wv][lane] = rs;
    __syncthreads();
    if (tid < 16) {
        float s = 0.f;
        #pragma unroll
        for (int w = 0; w < 8; ++w) s += rsum[w][tid];
        i2s[tid] = 2.0f / s;       // includes dropout keep-scale
    }
    __syncthreads();

    // ---- CD phase (barrier-free): NT attn store + PV over our k-half ----
    const int cr = tid >> 5;            // 0..15
    const int cc = (tid & 31) * 8;      // col base within 256-stripe
    const int xc = (cr & 7) << 3;
    const float i2 = i2s[cr];
    const size_t crow = ((size_t)b * SQ + q0 + cr) * SQ + (size_t)kh * KH + cc;

    const int g   = wv >> 1;            // d-group 0..3
    const int par = wv & 1;             // k-parity within half
    const int xm  = (m16 & 7) << 3;
    const unsigned short* vrow = Vt + ((size_t)b * DK + g * 16 + m16) * SQ + (size_t)kh * KH;
    f32x4 acc = {0.f, 0.f, 0.f, 0.f};

    #define CSTRIPE(s)                                                            \
    {                                                                             \
        const u32x4 ev = *(const u32x4*)&e_half[cr][((s) * 256 + cc) ^ xc];       \
        f32x4 o0, o1;                                                             \
        o0[0] = bf2f(ev[0] & 0xffffu) * i2;  o0[1] = bf2f_hi(ev[0]) * i2;         \
        o0[2] = bf2f(ev[1] & 0xffffu) * i2;  o0[3] = bf2f_hi(ev[1]) * i2;         \
        o1[0] = bf2f(ev[2] & 0xffffu) * i2;  o1[1] = bf2f_hi(ev[2]) * i2;         \
        o1[2] = bf2f(ev[3] & 0xffffu) * i2;  o1[3] = bf2f_hi(ev[3]) * i2;         \
        __builtin_nontemporal_store(o0, (f32x4*)(Aout + crow + (s) * 256));       \
        __builtin_nontemporal_store(o1, (f32x4*)(Aout + crow + (s) * 256 + 4));   \
    }
    #define PVCHUNK4(c0)                                                          \
    {                                                                             \
        _Pragma("unroll")                                                         \
        for (int c = (c0); c < (c0) + 4; ++c) {                                   \
            const int kl = par * 512 + c * 32;                                    \
            const short8 af = *(const short8*)&e_half[m16][(kl + koff) ^ xm];     \
            const short8 vf = *(const short8*)(vrow + kl + koff);                 \
            acc = __builtin_amdgcn_mfma_f32_16x16x32_bf16(af, vf, acc, 0, 0, 0);  \
        }                                                                         \
    }

    CSTRIPE(0) PVCHUNK4(0)
    CSTRIPE(1) PVCHUNK4(4)
    CSTRIPE(2) PVCHUNK4(8)
    CSTRIPE(3) PVCHUNK4(12)

    #undef PVCHUNK4
    #undef CSTRIPE

    // ---- combine k-parities, normalize, write y-partial for this half ----
    if (par == 1) {
        #pragma unroll
        for (int r = 0; r < 4; ++r) yp[g][kq * 4 + r][m16] = acc[r];
    }
    __syncthreads();
    if (par == 0) {
        #pragma unroll
        for (int r = 0; r < 4; ++r) {
            const int row = kq * 4 + r;
            const float yv = (acc[r] + yp[g][row][m16]) * i2s[row];
            __builtin_nontemporal_store(yv,
                Yp + ((size_t)(kh * NB + b) * SQ + q0 + row) * DK + g * 16 + m16);
        }
    }
}

// ============ y reduction: sum the two k-half partials ============
__global__ __launch_bounds__(256) void yred_kernel(
    const float* __restrict__ Yp, float* __restrict__ Yout)
{
    const size_t NEL = (size_t)NB * SQ * DK;
    const size_t i = ((size_t)blockIdx.x * 256 + threadIdx.x) * 4;
    f32x4 a = *(const f32x4*)(Yp + i);
    f32x4 b = *(const f32x4*)(Yp + NEL + i);
    f32x4 s = a + b;
    __builtin_nontemporal_store(s, (f32x4*)(Yout + i));
}

extern "C" void kernel_launch(void* const* d_in, const int* in_sizes, int n_in,
                              void* d_out, int out_size, void* d_ws, size_t ws_size,
                              hipStream_t stream) {
    const float*    Q  = (const float*)d_in[0];
    const float*    K  = (const float*)d_in[1];
    const float*    V  = (const float*)d_in[2];
    const unsigned* Mk = (const unsigned*)d_in[3];
    float* Yout = (float*)d_out;
    float* Aout = (float*)d_out + (size_t)NB * SQ * DK;

    const size_t NEL = (size_t)NB * SQ * DK;
    unsigned short* Khi = (unsigned short*)d_ws;
    unsigned short* Klo = Khi + NEL;
    unsigned short* Vt  = Klo + NEL;
    unsigned*       Mkb = (unsigned*)(Vt + NEL);        // 16.8 MB
    float*          Yp  = (float*)(Mkb + NEL / 2);      // 2 * NEL floats

    const int NPREP = NB * 32;                                    // 1024
    const int NMKP  = (int)((size_t)NB * SQ * (SQ / 32) / 256);   // 16384
    prep_kernel<<<dim3(NPREP + NMKP), dim3(256), 0, stream>>>(K, V, Mk, Khi, Klo, Vt, Mkb);
    sdpa_main<<<dim3(NB * (SQ / TQ) * 2), dim3(512), 0, stream>>>(
        Q, Khi, Klo, Vt, Mkb, Yp, Aout);
    yred_kernel<<<dim3((unsigned)(NEL / 1024)), dim3(256), 0, stream>>>(Yp, Yout);
}

// Round 16
// 462.546 us; speedup vs baseline: 1.8465x; 1.8465x over previous
//
#include <hip/hip_runtime.h>
#include <hip/hip_bf16.h>
#include <stdint.h>

#define SQ 2048
#define DK 64
#define NB 32
#define TQ 32              // q rows per block
#define EW 2064            // bf16 elems per LDS score row (pad)
#define SCL 0.18033688011112042f   // log2(e)/8

typedef __attribute__((ext_vector_type(8))) short short8;
typedef __attribute__((ext_vector_type(4))) float f32x4;
typedef __attribute__((ext_vector_type(4))) unsigned u32x4;
typedef __attribute__((ext_vector_type(2))) unsigned u32x2;

// ---- bf16 helpers ----
__device__ __forceinline__ unsigned f2bf_u(float x) {
    unsigned u = __builtin_bit_cast(unsigned, x);
    u += 0x7fffu + ((u >> 16) & 1u);
    return u >> 16;
}
__device__ __forceinline__ float bf2f(unsigned h) {
    return __builtin_bit_cast(float, h << 16);
}
__device__ __forceinline__ float bf2f_hi(unsigned u) {
    return __builtin_bit_cast(float, u & 0xffff0000u);
}
__device__ __forceinline__ unsigned cvtpk_bf16(float lo, float hi) {
    unsigned r;
    asm("v_cvt_pk_bf16_f32 %0, %1, %2" : "=v"(r) : "v"(lo), "v"(hi));
    return r;
}
__device__ __forceinline__ void split8(const float* p, short8& h, short8& l) {
    f32x4 a = *(const f32x4*)p;
    f32x4 b = *(const f32x4*)(p + 4);
    #pragma unroll
    for (int j = 0; j < 4; ++j) {
        unsigned ua = f2bf_u(a[j]);
        h[j] = (short)ua; l[j] = (short)f2bf_u(a[j] - bf2f(ua));
        unsigned ub = f2bf_u(b[j]);
        h[j + 4] = (short)ub; l[j + 4] = (short)f2bf_u(b[j] - bf2f(ub));
    }
}

// ============ fused prep: K planes + Vt transpose + mask bitpack ============
__global__ __launch_bounds__(256) void prep_kernel(
    const float* __restrict__ K, const float* __restrict__ V,
    const unsigned* __restrict__ Mk,
    unsigned short* __restrict__ Khi, unsigned short* __restrict__ Klo,
    unsigned short* __restrict__ Vt, unsigned* __restrict__ Mkb)
{
    __shared__ float vtile[64][65];
    const int t = threadIdx.x;

    if (blockIdx.x >= NB * 32) {
        const size_t w = (size_t)(blockIdx.x - NB * 32) * 256 + t;
        const unsigned* p = Mk + w * 32;
        unsigned bits = 0;
        #pragma unroll
        for (int j = 0; j < 8; ++j) {
            const u32x4 v = *(const u32x4*)(p + j * 4);
            bits |= (v[0] ? 1u : 0u) << (j * 4 + 0);
            bits |= (v[1] ? 1u : 0u) << (j * 4 + 1);
            bits |= (v[2] ? 1u : 0u) << (j * 4 + 2);
            bits |= (v[3] ? 1u : 0u) << (j * 4 + 3);
        }
        Mkb[w] = bits;
        return;
    }

    const int b  = blockIdx.x >> 5;
    const int s0 = (blockIdx.x & 31) << 6;
    const size_t base = ((size_t)b * SQ + s0) * DK + (size_t)t * 16;

    {
        short8 h0, l0, h1, l1;
        split8(K + base,     h0, l0);
        split8(K + base + 8, h1, l1);
        *(short8*)(Khi + base)     = h0;
        *(short8*)(Khi + base + 8) = h1;
        *(short8*)(Klo + base)     = l0;
        *(short8*)(Klo + base + 8) = l1;
    }
    {
        const int sr = t >> 2, dc = (t & 3) << 4;
        #pragma unroll
        for (int u = 0; u < 16; u += 4) {
            f32x4 v = *(const f32x4*)(V + base + u);
            vtile[sr][dc + u + 0] = v[0];
            vtile[sr][dc + u + 1] = v[1];
            vtile[sr][dc + u + 2] = v[2];
            vtile[sr][dc + u + 3] = v[3];
        }
    }
    __syncthreads();
    #pragma unroll
    for (int rep = 0; rep < 16; ++rep) {
        const int idx = rep * 256 + t;
        const int d = idx >> 6, s = idx & 63;
        Vt[((size_t)b * DK + d) * SQ + s0 + s] = (unsigned short)f2bf_u(vtile[s][d]);
    }
}

// ============ main: TQ=32, 16 waves, double-buffered K, loads-before-stores ============
__global__ __launch_bounds__(1024, 4) void sdpa_main(
    const float* __restrict__ Q, const unsigned short* __restrict__ Khi,
    const unsigned short* __restrict__ Klo, const unsigned short* __restrict__ Vt,
    const unsigned* __restrict__ Mkb, float* __restrict__ Yout, float* __restrict__ Aout)
{
    __shared__ __align__(16) unsigned short e_lds[TQ][EW];  // 132096 B, masked-e bf16
    __shared__ float yp[2][4][16][16];                      // 8 KB
    __shared__ float rsum[16][TQ];                          // 2 KB
    __shared__ float i2s[TQ];

    const int tid  = threadIdx.x;
    const int lane = tid & 63;
    const int wv   = tid >> 6;          // 0..15
    const int m16  = lane & 15;
    const int kq   = lane >> 4;
    const int koff = kq * 8;

    // XCD batch-affinity swizzle: XCD x owns batches 4x..4x+3
    const int bx  = blockIdx.x;
    const int xcd = bx & 7;
    const int j   = bx >> 3;            // 0..255
    const int b   = xcd * 4 + (j >> 6);
    const int q0  = (j & 63) * TQ;

    // Q fragments for BOTH q-halves (B-operand), split bf16
    short8 qh0[2], ql0[2], qh1[2], ql1[2];
    {
        const float* qr0 = Q + ((size_t)b * SQ + q0 + m16) * DK;
        split8(qr0 + koff,      qh0[0], ql0[0]);
        split8(qr0 + 32 + koff, qh0[1], ql0[1]);
        const float* qr1 = qr0 + 16 * DK;
        split8(qr1 + koff,      qh1[0], ql1[0]);
        split8(qr1 + 32 + koff, qh1[1], ql1[1]);
    }

    // bitmask for this wave's 128-k strip (L2-resident)
    const int ks = wv;
    const u32x4 mw0 = *(const u32x4*)(Mkb + ((size_t)b * SQ + q0 + m16) * (SQ / 32) + ks * 4);
    const u32x4 mw1 = *(const u32x4*)(Mkb + ((size_t)b * SQ + q0 + 16 + m16) * (SQ / 32) + ks * 4);

    // ---- Phase A: e = mask * exp(QK^T/8) for both q-halves -> bf16 LDS ----
    float rs0 = 0.f, rs1 = 0.f;
    {
        const size_t krow = ((size_t)b * SQ + ks * 128 + m16) * DK;
        const unsigned short* khp = Khi + krow;
        const unsigned short* klp = Klo + krow;
        const int xw = (m16 & 7) << 3;

        // double-buffered K fragments: load t+1 before computing t
        short8 ka0, ka1, la0, la1;      // slot A (even t)
        short8 kb0, kb1, lb0, lb1;      // slot B (odd t)

        #define KLOADA(t) {                                                \
            const int off = (t) * 16 * DK;                                 \
            ka0 = *(const short8*)(khp + off + koff);                      \
            ka1 = *(const short8*)(khp + off + 32 + koff);                 \
            la0 = *(const short8*)(klp + off + koff);                      \
            la1 = *(const short8*)(klp + off + 32 + koff); }
        #define KLOADB(t) {                                                \
            const int off = (t) * 16 * DK;                                 \
            kb0 = *(const short8*)(khp + off + koff);                      \
            kb1 = *(const short8*)(khp + off + 32 + koff);                 \
            lb0 = *(const short8*)(klp + off + koff);                      \
            lb1 = *(const short8*)(klp + off + 32 + koff); }

        #define AITER2(t, K0, K1, L0, L1)                                                   \
        {                                                                                   \
            /* q-half 0 */                                                                  \
            {                                                                               \
                f32x4 a0 = {0.f, 0.f, 0.f, 0.f};                                            \
                f32x4 a1 = {0.f, 0.f, 0.f, 0.f};                                            \
                a0 = __builtin_amdgcn_mfma_f32_16x16x32_bf16(K0, qh0[0], a0, 0, 0, 0);      \
                a1 = __builtin_amdgcn_mfma_f32_16x16x32_bf16(K1, qh0[1], a1, 0, 0, 0);      \
                a0 = __builtin_amdgcn_mfma_f32_16x16x32_bf16(K0, ql0[0], a0, 0, 0, 0);      \
                a1 = __builtin_amdgcn_mfma_f32_16x16x32_bf16(K1, ql0[1], a1, 0, 0, 0);      \
                a0 = __builtin_amdgcn_mfma_f32_16x16x32_bf16(L0, qh0[0], a0, 0, 0, 0);      \
                a1 = __builtin_amdgcn_mfma_f32_16x16x32_bf16(L1, qh0[1], a1, 0, 0, 0);      \
                const float e0 = __builtin_amdgcn_exp2f((a0[0] + a1[0]) * SCL);             \
                const float e1 = __builtin_amdgcn_exp2f((a0[1] + a1[1]) * SCL);             \
                const float e2 = __builtin_amdgcn_exp2f((a0[2] + a1[2]) * SCL);             \
                const float e3 = __builtin_amdgcn_exp2f((a0[3] + a1[3]) * SCL);             \
                rs0 += (e0 + e1) + (e2 + e3);                                               \
                const unsigned bits = (mw0[(t) >> 1] >> (((t) & 1) * 16 + kq * 4)) & 0xfu;  \
                const float p0 = (bits & 1u) ? e0 : 0.f;                                    \
                const float p1 = (bits & 2u) ? e1 : 0.f;                                    \
                const float p2 = (bits & 4u) ? e2 : 0.f;                                    \
                const float p3 = (bits & 8u) ? e3 : 0.f;                                    \
                u32x2 pk;                                                                   \
                pk[0] = cvtpk_bf16(p0, p1);                                                 \
                pk[1] = cvtpk_bf16(p2, p3);                                                 \
                *(u32x2*)&e_lds[m16][(ks * 128 + (t) * 16 + kq * 4) ^ xw] = pk;             \
            }                                                                               \
            /* q-half 1 */                                                                  \
            {                                                                               \
                f32x4 a0 = {0.f, 0.f, 0.f, 0.f};                                            \
                f32x4 a1 = {0.f, 0.f, 0.f, 0.f};                                            \
                a0 = __builtin_amdgcn_mfma_f32_16x16x32_bf16(K0, qh1[0], a0, 0, 0, 0);      \
                a1 = __builtin_amdgcn_mfma_f32_16x16x32_bf16(K1, qh1[1], a1, 0, 0, 0);      \
                a0 = __builtin_amdgcn_mfma_f32_16x16x32_bf16(K0, ql1[0], a0, 0, 0, 0);      \
                a1 = __builtin_amdgcn_mfma_f32_16x16x32_bf16(K1, ql1[1], a1, 0, 0, 0);      \
                a0 = __builtin_amdgcn_mfma_f32_16x16x32_bf16(L0, qh1[0], a0, 0, 0, 0);      \
                a1 = __builtin_amdgcn_mfma_f32_16x16x32_bf16(L1, qh1[1], a1, 0, 0, 0);      \
                const float e0 = __builtin_amdgcn_exp2f((a0[0] + a1[0]) * SCL);             \
                const float e1 = __builtin_amdgcn_exp2f((a0[1] + a1[1]) * SCL);             \
                const float e2 = __builtin_amdgcn_exp2f((a0[2] + a1[2]) * SCL);             \
                const float e3 = __builtin_amdgcn_exp2f((a0[3] + a1[3]) * SCL);             \
                rs1 += (e0 + e1) + (e2 + e3);                                               \
                const unsigned bits = (mw1[(t) >> 1] >> (((t) & 1) * 16 + kq * 4)) & 0xfu;  \
                const float p0 = (bits & 1u) ? e0 : 0.f;                                    \
                const float p1 = (bits & 2u) ? e1 : 0.f;                                    \
                const float p2 = (bits & 4u) ? e2 : 0.f;                                    \
                const float p3 = (bits & 8u) ? e3 : 0.f;                                    \
                u32x2 pk;                                                                   \
                pk[0] = cvtpk_bf16(p0, p1);                                                 \
                pk[1] = cvtpk_bf16(p2, p3);                                                 \
                *(u32x2*)&e_lds[16 + m16][(ks * 128 + (t) * 16 + kq * 4) ^ xw] = pk;        \
            }                                                                               \
        }

        KLOADA(0)
        KLOADB(1) AITER2(0, ka0, ka1, la0, la1)
        KLOADA(2) AITER2(1, kb0, kb1, lb0, lb1)
        KLOADB(3) AITER2(2, ka0, ka1, la0, la1)
        KLOADA(4) AITER2(3, kb0, kb1, lb0, lb1)
        KLOADB(5) AITER2(4, ka0, ka1, la0, la1)
        KLOADA(6) AITER2(5, kb0, kb1, lb0, lb1)
        KLOADB(7) AITER2(6, ka0, ka1, la0, la1)
                  AITER2(7, kb0, kb1, lb0, lb1)

        #undef AITER2
        #undef KLOADB
        #undef KLOADA
    }
    rs0 += __shfl_xor(rs0, 16);
    rs0 += __shfl_xor(rs0, 32);
    rs1 += __shfl_xor(rs1, 16);
    rs1 += __shfl_xor(rs1, 32);
    if (lane < 16) {
        rsum[wv][lane]      = rs0;
        rsum[wv][16 + lane] = rs1;
    }
    __syncthreads();
    if (tid < TQ) {
        float s = 0.f;
        #pragma unroll
        for (int w = 0; w < 16; ++w) s += rsum[w][tid];
        i2s[tid] = 2.0f / s;       // includes dropout keep-scale
    }
    __syncthreads();

    // ---- CD phase (barrier-free): PV loads issued BEFORE attn stores (vmcnt FIFO) ----
    const int cr = tid >> 5;            // 0..31 (attn row)
    const int cc = (tid & 31) * 8;      // col base within 256-stripe
    const int xc = (cr & 7) << 3;
    const float i2 = i2s[cr];
    const size_t crow = ((size_t)b * SQ + q0 + cr) * SQ + cc;

    const int qg  = wv >> 3;            // q-half
    const int g   = (wv >> 1) & 3;      // d-group
    const int par = wv & 1;             // k-parity (1024 each)
    const int erow = qg * 16 + m16;
    const int xe  = (erow & 7) << 3;
    const unsigned short* vrow = Vt + ((size_t)b * DK + g * 16 + m16) * SQ + par * 1024;
    f32x4 acc = {0.f, 0.f, 0.f, 0.f};

    #define PVCHUNK4(c0)                                                          \
    {                                                                             \
        _Pragma("unroll")                                                         \
        for (int c = (c0); c < (c0) + 4; ++c) {                                   \
            const int kl = par * 1024 + c * 32;                                   \
            const short8 af = *(const short8*)&e_lds[erow][(kl + koff) ^ xe];     \
            const short8 vf = *(const short8*)(vrow + c * 32 + koff);             \
            acc = __builtin_amdgcn_mfma_f32_16x16x32_bf16(af, vf, acc, 0, 0, 0);  \
        }                                                                         \
    }
    #define CSTRIPE(s)                                                            \
    {                                                                             \
        const u32x4 ev = *(const u32x4*)&e_lds[cr][((s) * 256 + cc) ^ xc];        \
        f32x4 o0, o1;                                                             \
        o0[0] = bf2f(ev[0] & 0xffffu) * i2;  o0[1] = bf2f_hi(ev[0]) * i2;         \
        o0[2] = bf2f(ev[1] & 0xffffu) * i2;  o0[3] = bf2f_hi(ev[1]) * i2;         \
        o1[0] = bf2f(ev[2] & 0xffffu) * i2;  o1[1] = bf2f_hi(ev[2]) * i2;         \
        o1[2] = bf2f(ev[3] & 0xffffu) * i2;  o1[3] = bf2f_hi(ev[3]) * i2;         \
        __builtin_nontemporal_store(o0, (f32x4*)(Aout + crow + (s) * 256));       \
        __builtin_nontemporal_store(o1, (f32x4*)(Aout + crow + (s) * 256 + 4));   \
    }

    PVCHUNK4(0)  CSTRIPE(0)
    PVCHUNK4(4)  CSTRIPE(1)
    PVCHUNK4(8)  CSTRIPE(2)
    PVCHUNK4(12) CSTRIPE(3)
    PVCHUNK4(16) CSTRIPE(4)
    PVCHUNK4(20) CSTRIPE(5)
    PVCHUNK4(24) CSTRIPE(6)
    PVCHUNK4(28) CSTRIPE(7)

    #undef CSTRIPE
    #undef PVCHUNK4

    // ---- combine k-parities, normalize, write y ----
    if (par == 1) {
        #pragma unroll
        for (int r = 0; r < 4; ++r) yp[qg][g][kq * 4 + r][m16] = acc[r];
    }
    __syncthreads();
    if (par == 0) {
        #pragma unroll
        for (int r = 0; r < 4; ++r) {
            const float yv = (acc[r] + yp[qg][g][kq * 4 + r][m16]) * i2s[qg * 16 + kq * 4 + r];
            Yout[((size_t)b * SQ + q0 + qg * 16 + kq * 4 + r) * DK + g * 16 + m16] = yv;
        }
    }
}

extern "C" void kernel_launch(void* const* d_in, const int* in_sizes, int n_in,
                              void* d_out, int out_size, void* d_ws, size_t ws_size,
                              hipStream_t stream) {
    const float*    Q  = (const float*)d_in[0];
    const float*    K  = (const float*)d_in[1];
    const float*    V  = (const float*)d_in[2];
    const unsigned* Mk = (const unsigned*)d_in[3];
    float* Yout = (float*)d_out;
    float* Aout = (float*)d_out + (size_t)NB * SQ * DK;

    const size_t NEL = (size_t)NB * SQ * DK;
    unsigned short* Khi = (unsigned short*)d_ws;
    unsigned short* Klo = Khi + NEL;
    unsigned short* Vt  = Klo + NEL;
    unsigned*       Mkb = (unsigned*)(Vt + NEL);   // 16.8 MB

    const int NPREP = NB * 32;                                    // 1024
    const int NMKP  = (int)((size_t)NB * SQ * (SQ / 32) / 256);   // 16384
    prep_kernel<<<dim3(NPREP + NMKP), dim3(256), 0, stream>>>(K, V, Mk, Khi, Klo, Vt, Mkb);
    sdpa_main<<<dim3(NB * (SQ / TQ)), dim3(1024), 0, stream>>>(
        Q, Khi, Klo, Vt, Mkb, Yout, Aout);
}